// Round 2
// baseline (223.846 us; speedup 1.0000x reference)
//
#include <hip/hip_runtime.h>

typedef __attribute__((ext_vector_type(8))) short short8;
typedef __attribute__((ext_vector_type(4))) float floatx4;

#define IN_C 128
#define OUT_C 256
#define NB 32
#define HW 56
#define S_PER_N (HW * HW)          // 3136
#define M_TOTAL (NB * S_PER_N)     // 100352
#define PH 58                      // padded height
#define PW 66                      // padded width
#define XN_ELEMS (NB * PH * PW * IN_C)   // 15,679,488
#define WT_ELEMS (9 * OUT_C * IN_C)      // 294,912

__device__ __forceinline__ unsigned short f2bf(float f) {
    unsigned int u = __builtin_bit_cast(unsigned int, f);
    u = (u + 0x7FFFu + ((u >> 16) & 1u)) >> 16;   // RNE
    return (unsigned short)u;
}

// Direct global->LDS DMA, 16B per lane. LDS dest must be base + lane*16.
__device__ __forceinline__ void gld_lds16(const unsigned short* g, unsigned short* l) {
    __builtin_amdgcn_global_load_lds(
        (const __attribute__((address_space(1))) unsigned int*)g,
        (__attribute__((address_space(3))) unsigned int*)l, 16, 0, 0);
}

// x (N,C,56,56) fp32  ->  xn (N,58,66,C) bf16 with zero halo baked in.
__global__ void xform_x(const float* __restrict__ x, unsigned short* __restrict__ xn) {
    const int ihp = blockIdx.x;          // 0..57
    const int n   = blockIdx.y;          // 0..31
    const int tid = threadIdx.x;         // 256 threads
    unsigned int* __restrict__ row32 =
        (unsigned int*)(xn + (size_t)(n * PH + ihp) * PW * IN_C);
    const int WORDS = PW * IN_C / 2;     // 4224 uint32 per row

    if (ihp == 0 || ihp == PH - 1) {
        for (int i = tid; i < WORDS; i += 256) row32[i] = 0u;
        return;
    }
    const int ih = ihp - 1;
    __shared__ unsigned short lds2[HW][IN_C];   // [iw][ic] bf16, 14336 B
    const float* __restrict__ xrow = x + (size_t)n * IN_C * S_PER_N + (size_t)ih * HW;
    for (int i = tid; i < IN_C * 14; i += 256) {   // float4 per (ic, iw4)
        int ic = i / 14, iw4 = (i % 14) * 4;
        float4 v = *(const float4*)(xrow + (size_t)ic * S_PER_N + iw4);
        lds2[iw4 + 0][ic] = f2bf(v.x);
        lds2[iw4 + 1][ic] = f2bf(v.y);
        lds2[iw4 + 2][ic] = f2bf(v.z);
        lds2[iw4 + 3][ic] = f2bf(v.w);
    }
    __syncthreads();
    for (int wi = tid; wi < WORDS; wi += 256) {
        int pix = wi >> 6;               // 0..65
        int icw = wi & 63;               // ic pair index
        unsigned int val = 0u;
        if (pix >= 1 && pix <= HW)
            val = *(const unsigned int*)&lds2[pix - 1][icw * 2];
        row32[wi] = val;
    }
}

// w (256,128,3,3) fp32 -> wt[khw][oc][ic] bf16
__global__ void xform_w(const float* __restrict__ w, unsigned short* __restrict__ wt) {
    const int idx = blockIdx.x * 256 + threadIdx.x;   // grid exact
    const int ic  = idx & 127;
    const int oc  = (idx >> 7) & 255;
    const int khw = idx >> 15;
    wt[idx] = f2bf(w[(oc * IN_C + ic) * 9 + khw]);
}

// Implicit GEMM, 8-phase-style schedule (T3+T4+T5 on top of T1+T2):
//   tile 256 s x 256 oc, BK=64, 512 thr / 8 waves (2 oc-halves x 4 s-quarters),
//   per wave 128 oc x 64 s = acc[8][4]. LDS double-buffered 128 KB -> 1 block/CU.
// Per K-tile (18 total = 9 khw x 2 ic-halves, buffer parity = ic-half h):
//   burst-stage next tile (8 gld_lds -> other buffer)   [latency hidden under phases]
//   4 quadrant phases: 12 ds_read_b128 -> setprio(1) 16 MFMA setprio(0) -> raw barrier
//   tile boundary: s_waitcnt vmcnt(0) + barrier (only vmem drain point, ~4 phases of cover)
// T21 swizzle (slot u ^= row&7, source-side + read-side) carried over: 0 bank conflicts.
// T1 bijective XCD swizzle: grid 392 = 8*49.
__global__ void __launch_bounds__(512, 2)
conv_mfma(const unsigned short* __restrict__ xn,
          const unsigned short* __restrict__ wt,
          float* __restrict__ out) {
    const int tid  = threadIdx.x;     // 0..511
    const int lane = tid & 63;
    const int wv   = tid >> 6;        // 0..7
    const int wm   = wv >> 2;         // 0..1  oc half (128 rows)
    const int wn   = wv & 3;          // 0..3  s quarter (64 rows)
    const int l15  = lane & 15;
    const int quad = lane >> 4;       // 0..3
    const int fr7  = l15 & 7;

    const int bx0    = blockIdx.x;                    // 0..391
    const int tile_m = (bx0 & 7) * 49 + (bx0 >> 3);   // XCD-contiguous remap
    const int s_blk  = tile_m * 256;

    __shared__ unsigned short A_lds[2][256 * 64];   // weights [oc][ic64], 2x32KB
    __shared__ unsigned short B_lds[2][256 * 64];   // acts    [s][ic64],  2x32KB

    // ---- staging: 8 gld_lds per tile; call g covers rows g*64 + (tid>>3) ----
    const int srow = tid >> 3;                        // 0..63
    const int sic  = ((tid & 7) ^ (srow & 7)) * 8;    // T21 source-side swizzle

    const unsigned short* a_g[4];
    const unsigned short* b_g[4];
#pragma unroll
    for (int g = 0; g < 4; ++g) {
        int row = g * 64 + srow;                      // row&7 == srow&7
        a_g[g] = wt + (size_t)row * IN_C + sic;
        int sg = s_blk + row;
        int n  = sg / S_PER_N;
        int r2 = sg % S_PER_N;
        int oh = r2 / HW, ow = r2 % HW;
        b_g[g] = xn + (size_t)((n * PH + oh) * PW + ow) * IN_C + sic;
    }

    // ---- fragment read bases (elements); read-side swizzle matches source ----
    // elem(row, kk) = row*64 + (((quad)^(row&7))*8 ^ kk*32), row&7 == fr7
    const int slot = (quad ^ fr7) * 8;
    int a_base[2], b_base[2];
#pragma unroll
    for (int kk = 0; kk < 2; ++kk) {
        a_base[kk] = (wm * 128 + l15) * 64 + (slot ^ (kk * 32));
        b_base[kk] = (wn * 64  + l15) * 64 + (slot ^ (kk * 32));
    }

    floatx4 acc[8][4];
#pragma unroll
    for (int i = 0; i < 8; ++i)
#pragma unroll
        for (int j = 0; j < 4; ++j) acc[i][j] = (floatx4){0.f, 0.f, 0.f, 0.f};

    // ---- prologue: stage tile (khw=0, h=0) into buffer 0 ----
#pragma unroll
    for (int g = 0; g < 4; ++g) {
        gld_lds16(a_g[g], &A_lds[0][g * 4096 + tid * 8]);
        gld_lds16(b_g[g], &B_lds[0][g * 4096 + tid * 8]);
    }
    asm volatile("s_waitcnt vmcnt(0)" ::: "memory");
    __builtin_amdgcn_s_barrier();

    int xo = 0;
#pragma unroll 1
    for (int khw = 0; khw < 9; ++khw) {
        const int wo  = khw * (OUT_C * IN_C);
        const int kwv = khw - (khw / 3) * 3;          // khw % 3
        const int xo_next = (kwv == 2) ? (xo + (PW - 2) * IN_C) : (xo + IN_C);
#pragma unroll
        for (int h = 0; h < 2; ++h) {                 // K-tile lives in buffer h
            // -- burst-stage the NEXT K-tile into buffer 1-h --
            if (khw < 8 || h == 0) {
                const int awo = (h == 0) ? (wo + 64) : (wo + OUT_C * IN_C);
                const int bxo = (h == 0) ? (xo + 64) : xo_next;
#pragma unroll
                for (int g = 0; g < 4; ++g) {
                    gld_lds16(a_g[g] + awo, &A_lds[1 - h][g * 4096 + tid * 8]);
                    gld_lds16(b_g[g] + bxo, &B_lds[1 - h][g * 4096 + tid * 8]);
                }
            }
            const unsigned short* Ab = &A_lds[h][0];
            const unsigned short* Bb = &B_lds[h][0];
            // -- 4 quadrant phases --
#pragma unroll
            for (int q = 0; q < 4; ++q) {
                const int mh = q >> 1, nh = q & 1;
                short8 a[4][2], b[2][2];
#pragma unroll
                for (int kk = 0; kk < 2; ++kk) {
#pragma unroll
                    for (int ii = 0; ii < 4; ++ii)
                        a[ii][kk] = *(const short8*)(Ab + a_base[kk] + (mh * 4 + ii) * 1024);
#pragma unroll
                    for (int jj = 0; jj < 2; ++jj)
                        b[jj][kk] = *(const short8*)(Bb + b_base[kk] + (nh * 2 + jj) * 1024);
                }
                __builtin_amdgcn_s_setprio(1);
#pragma unroll
                for (int kk = 0; kk < 2; ++kk)
#pragma unroll
                    for (int ii = 0; ii < 4; ++ii)
#pragma unroll
                        for (int jj = 0; jj < 2; ++jj)
                            acc[mh * 4 + ii][nh * 2 + jj] =
                                __builtin_amdgcn_mfma_f32_16x16x32_bf16(
                                    a[ii][kk], b[jj][kk],
                                    acc[mh * 4 + ii][nh * 2 + jj], 0, 0, 0);
                __builtin_amdgcn_s_setprio(0);
                __builtin_amdgcn_s_barrier();         // phase lockstep (no vmem drain)
            }
            // -- tile boundary: staged tile must have landed, block-wide --
            asm volatile("s_waitcnt vmcnt(0)" ::: "memory");
            __builtin_amdgcn_s_barrier();
        }
        xo = xo_next;
    }

    // ---- epilogue: C/D layout col=lane&15 (s), row=quad*4+reg (oc) ----
    const int s0  = s_blk + wn * 64;
    const int oc0 = wm * 128;
#pragma unroll
    for (int j = 0; j < 4; ++j) {
        int s_glob = s0 + j * 16 + l15;
        int n = s_glob / S_PER_N;
        int s = s_glob % S_PER_N;
        float* obase = out + (size_t)n * OUT_C * S_PER_N + s;
#pragma unroll
        for (int i = 0; i < 8; ++i) {
            int oc = oc0 + i * 16 + quad * 4;
#pragma unroll
            for (int r = 0; r < 4; ++r)
                obase[(size_t)(oc + r) * S_PER_N] = acc[i][j][r];
        }
    }
}

extern "C" void kernel_launch(void* const* d_in, const int* in_sizes, int n_in,
                              void* d_out, int out_size, void* d_ws, size_t ws_size,
                              hipStream_t stream) {
    const float* x = (const float*)d_in[0];
    const float* w = (const float*)d_in[1];
    float* out = (float*)d_out;

    unsigned short* xn = (unsigned short*)d_ws;      // 31,358,976 B
    unsigned short* wt = xn + XN_ELEMS;              // 589,824 B

    dim3 gx(PH, NB);
    xform_x<<<gx, 256, 0, stream>>>(x, xn);
    xform_w<<<WT_ELEMS / 256, 256, 0, stream>>>(w, wt);
    conv_mfma<<<M_TOTAL / 256, 512, 0, stream>>>(xn, wt, out);
}

// Round 3
// 203.590 us; speedup vs baseline: 1.0995x; 1.0995x over previous
//
#include <hip/hip_runtime.h>

typedef __attribute__((ext_vector_type(8))) short short8;
typedef __attribute__((ext_vector_type(4))) float floatx4;

#define IN_C 128
#define OUT_C 256
#define NB 32
#define HW 56
#define S_PER_N (HW * HW)          // 3136
#define M_TOTAL (NB * S_PER_N)     // 100352
#define PH 58                      // padded height
#define PW 66                      // padded width
#define XN_ELEMS (NB * PH * PW * IN_C)   // 15,679,488
#define WT_ELEMS (9 * OUT_C * IN_C)      // 294,912
#define XF_BLOCKS (PH * NB)              // 1856 transform-x blocks
#define WF_BLOCKS (WT_ELEMS / 256)       // 1152 weight blocks

__device__ __forceinline__ unsigned short f2bf(float f) {
    unsigned int u = __builtin_bit_cast(unsigned int, f);
    u = (u + 0x7FFFu + ((u >> 16) & 1u)) >> 16;   // RNE
    return (unsigned short)u;
}

// Direct global->LDS DMA, 16B per lane. LDS dest must be base + lane*16.
__device__ __forceinline__ void gld_lds16(const unsigned short* g, unsigned short* l) {
    __builtin_amdgcn_global_load_lds(
        (const __attribute__((address_space(1))) unsigned int*)g,
        (__attribute__((address_space(3))) unsigned int*)l, 16, 0, 0);
}

// Fused transform kernel, 1D grid = XF_BLOCKS + WF_BLOCKS.
//   bid < XF_BLOCKS: x (N,C,56,56) fp32 -> xn (N,58,66,C) bf16, halo baked in.
//     No LDS: the block's input slice (128ch x 224B = 28KB) sits in L1, so the
//     C-major->C-minor transpose rides L1 hits. Lane reads float4 from channel
//     pair (16B coalesced-ish, L1-resident after first touch), emits 4 packed
//     u32 stores; each store instr = 64 lanes x 4B contiguous = 256B. No barriers.
//   bid >= XF_BLOCKS: w (256,128,3,3) fp32 -> wt[khw][oc][ic] bf16.
__global__ void xform_all(const float* __restrict__ x, const float* __restrict__ w,
                          unsigned short* __restrict__ xn, unsigned short* __restrict__ wt) {
    const int bid = blockIdx.x;
    const int tid = threadIdx.x;         // 256 threads

    if (bid >= XF_BLOCKS) {              // ---- weight transform ----
        const int idx = (bid - XF_BLOCKS) * 256 + tid;
        const int ic  = idx & 127;
        const int oc  = (idx >> 7) & 255;
        const int khw = idx >> 15;
        wt[idx] = f2bf(w[(oc * IN_C + ic) * 9 + khw]);
        return;
    }

    const int ihp = bid % PH;            // 0..57
    const int n   = bid / PH;            // 0..31
    unsigned int* __restrict__ row32 =
        (unsigned int*)(xn + (size_t)(n * PH + ihp) * PW * IN_C);
    const int WORDS = PW * IN_C / 2;     // 4224 uint32 per padded row

    if (ihp == 0 || ihp == PH - 1) {     // top/bottom halo rows
        for (int i = tid; i < WORDS; i += 256) row32[i] = 0u;
        return;
    }
    // left/right halo words (pix 0 and 65): 128 words
    if (tid < 128) {
        int p = (tid >> 6) * (PW - 1);   // 0 or 65
        row32[p * 64 + (tid & 63)] = 0u;
    }
    const int ih = ihp - 1;
    const float* __restrict__ xrow = x + (size_t)n * IN_C * S_PER_N + (size_t)ih * HW;
    // items: (icw 0..63) x (pix4 0..13) = 896; icw = channel-pair, pix4 = 4 pixels
#pragma unroll
    for (int t = 0; t < 4; ++t) {
        const int item = tid + t * 256;
        if (item >= 64 * 14) break;
        const int icw  = item & 63;
        const int pix4 = item >> 6;      // 0..13 -> iw 4*pix4..+3
        const float4 v0 = *(const float4*)(xrow + (size_t)(2 * icw)     * S_PER_N + pix4 * 4);
        const float4 v1 = *(const float4*)(xrow + (size_t)(2 * icw + 1) * S_PER_N + pix4 * 4);
        unsigned int* o = row32 + (pix4 * 4 + 1) * 64 + icw;
        o[0]   = (unsigned int)f2bf(v0.x) | ((unsigned int)f2bf(v1.x) << 16);
        o[64]  = (unsigned int)f2bf(v0.y) | ((unsigned int)f2bf(v1.y) << 16);
        o[128] = (unsigned int)f2bf(v0.z) | ((unsigned int)f2bf(v1.z) << 16);
        o[192] = (unsigned int)f2bf(v0.w) | ((unsigned int)f2bf(v1.w) << 16);
    }
}

// Implicit GEMM (round-1 winner, reverted byte-identical):
// LDS-staged via global_load_lds(16B), BK=64 (18 barrier-pairs),
// block 128 oc x 128 s, 4 waves, wave 64x64 (4x4 of 16x16x32 bf16 MFMA).
// T21 both-sides XOR swizzle (slot u ^= row&7): 0 bank conflicts.
// T1 bijective XCD swizzle: grid 1568 = 8*196.
// __launch_bounds__(256,3): 3 blocks/CU (LDS 32KB, regs<=170).
__global__ void __launch_bounds__(256, 3)
conv_mfma(const unsigned short* __restrict__ xn,
          const unsigned short* __restrict__ wt,
          float* __restrict__ out) {
    const int tid  = threadIdx.x;
    const int lane = tid & 63;
    const int wv   = tid >> 6;        // 0..3
    const int l15  = lane & 15;
    const int quad = lane >> 4;       // 0..3

    const int bx0 = blockIdx.x;
    const int bx  = (bx0 & 7) * 196 + (bx0 >> 3);   // XCD-contiguous remap
    const int tile_oc = bx & 1;       // 2 oc tiles of 128
    const int tile_m  = bx >> 1;      // 784 spatial tiles of 128

    const int s_blk  = tile_m * 128;
    const int oc_blk = tile_oc * 128;
    const int s0  = s_blk + (wv & 1) * 64;    // wave spatial base
    const int oc0 = oc_blk + (wv >> 1) * 64;  // wave oc base

    __shared__ unsigned short A_lds[128 * 64];   // [oc_local][ic64] 16 KB (slot-swizzled)
    __shared__ unsigned short B_lds[128 * 64];   // [s_local][ic64]  16 KB (slot-swizzled)

    // ---- staging addresses: thread covers (row = q*32 + tid>>3, slot = tid&7) ----
    // Source slot pre-swizzled: LDS[row][u] <- global slot u ^ (row&7).
    const int srow = tid >> 3;          // 0..31 ; (q*32+srow)&7 == srow&7 for all q
    const int sic  = ((tid & 7) ^ (srow & 7)) * 8;   // swizzled source elem offset

    const unsigned short* a_g[4];
    const unsigned short* b_g[4];
#pragma unroll
    for (int q = 0; q < 4; ++q) {
        int row = q * 32 + srow;
        a_g[q] = wt + (size_t)(oc_blk + row) * IN_C + sic;
        int sg = s_blk + row;
        int n  = sg / S_PER_N;
        int r  = sg % S_PER_N;
        int oh = r / HW, ow = r % HW;
        b_g[q] = xn + (size_t)((n * PH + oh) * PW + ow) * IN_C + sic;
    }
    // LDS dests: issue q at elem q*2048 + tid*8 (byte q*4096 + tid*16) -- linear
    unsigned short* a_l = A_lds + tid * 8;
    unsigned short* b_l = B_lds + tid * 8;

    // ---- fragment read offsets (elements), row stride 64, slot ^= row&7 ----
    // read elem = row*64 + ((quad + 4*kk) ^ (row&7))*8 ; row&7 == l15&7.
    // kk folds in as XOR with 32 (slot bit2) applied to the precomputed offset.
    const int fr7 = l15 & 7;
    int afo[4], bfo[4];
#pragma unroll
    for (int i = 0; i < 4; ++i)
        afo[i] = ((wv >> 1) * 64 + i * 16 + l15) * 64 + ((quad ^ fr7) * 8);
#pragma unroll
    for (int j = 0; j < 4; ++j)
        bfo[j] = ((wv & 1) * 64 + j * 16 + l15) * 64 + ((quad ^ fr7) * 8);

    floatx4 acc[4][4];
#pragma unroll
    for (int i = 0; i < 4; ++i)
#pragma unroll
        for (int j = 0; j < 4; ++j) acc[i][j] = (floatx4){0.f, 0.f, 0.f, 0.f};

#pragma unroll
    for (int khw = 0; khw < 9; ++khw) {
        const int xo = ((khw / 3) * PW + (khw % 3)) * IN_C;  // activation k-offset
        const int wo = khw * OUT_C * IN_C;                   // weight k-offset
#pragma unroll
        for (int h = 0; h < 2; ++h) {
            const int ic0 = h * 64;
            __syncthreads();                      // previous tile consumed
#pragma unroll
            for (int q = 0; q < 4; ++q) {
                gld_lds16(a_g[q] + wo + ic0, a_l + q * 2048);
                gld_lds16(b_g[q] + xo + ic0, b_l + q * 2048);
            }
            __syncthreads();                      // tile loaded (vmcnt drained)

#pragma unroll
            for (int kk = 0; kk < 2; ++kk) {
                const int ko = kk * 32;           // XOR-folded kk slot shift
                short8 a[4], b[4];
#pragma unroll
                for (int i = 0; i < 4; ++i) a[i] = *(const short8*)(A_lds + (afo[i] ^ ko));
#pragma unroll
                for (int j = 0; j < 4; ++j) b[j] = *(const short8*)(B_lds + (bfo[j] ^ ko));
#pragma unroll
                for (int i = 0; i < 4; ++i)
#pragma unroll
                    for (int j = 0; j < 4; ++j)
                        acc[i][j] = __builtin_amdgcn_mfma_f32_16x16x32_bf16(
                            a[i], b[j], acc[i][j], 0, 0, 0);
            }
        }
    }

    // Epilogue: C/D layout col=lane&15 (s), row=quad*4+reg (oc).
#pragma unroll
    for (int j = 0; j < 4; ++j) {
        int s_glob = s0 + j * 16 + l15;
        int n = s_glob / S_PER_N;
        int s = s_glob % S_PER_N;
        float* obase = out + (size_t)n * OUT_C * S_PER_N + s;
#pragma unroll
        for (int i = 0; i < 4; ++i) {
            int oc = oc0 + i * 16 + quad * 4;
#pragma unroll
            for (int r = 0; r < 4; ++r)
                obase[(size_t)(oc + r) * S_PER_N] = acc[i][j][r];
        }
    }
}

extern "C" void kernel_launch(void* const* d_in, const int* in_sizes, int n_in,
                              void* d_out, int out_size, void* d_ws, size_t ws_size,
                              hipStream_t stream) {
    const float* x = (const float*)d_in[0];
    const float* w = (const float*)d_in[1];
    float* out = (float*)d_out;

    unsigned short* xn = (unsigned short*)d_ws;      // 31,358,976 B
    unsigned short* wt = xn + XN_ELEMS;              // 589,824 B

    xform_all<<<XF_BLOCKS + WF_BLOCKS, 256, 0, stream>>>(x, w, xn, wt);
    conv_mfma<<<(M_TOTAL / 128) * 2, 256, 0, stream>>>(xn, wt, out);
}